// Round 6
// baseline (191.023 us; speedup 1.0000x reference)
//
#include <hip/hip_runtime.h>

#define INV_2PI 0.15915494309189535f

// diff_round(x) = x - sin(2*pi*x)/(2*pi).
// v_sin_f32 takes REVOLUTIONS: __builtin_amdgcn_sinf(x) == sin(2*pi*x).
__device__ __forceinline__ float dround(float x) {
    return __builtin_fmaf(-INV_2PI, __builtin_amdgcn_sinf(x), x);
}
__device__ __forceinline__ float hdr(float x) { return dround(dround(dround(x))); }

// Batched diff_round over N lanes-local values: two separated unrolled loops
// so the 16 v_sin issue back-to-back (independent) and latencies overlap.
template <int N>
__device__ __forceinline__ void dround_batch(float* c) {
    float s[N];
#pragma unroll
    for (int i = 0; i < N; ++i) s[i] = __builtin_amdgcn_sinf(c[i]);
#pragma unroll
    for (int i = 0; i < N; ++i) c[i] = __builtin_fmaf(-INV_2PI, s[i], c[i]);
}

// One wave (64 lanes) per (area, mask-variant); each lane owns 4 contiguous
// pixels (16 mask channels). All 16 channels kept live in c[16] so every
// diff_round stage is a batch of 16 independent sins -> trans-pipe ILP.
__global__ __launch_bounds__(256) void De_conv_areas_kernel(
    const float* __restrict__ img,       // [A,256,1] f32
    const float* __restrict__ mask,      // [A,256,4] f32
    const float* __restrict__ mask_alt,  // [A,256,4] f32
    const float* __restrict__ mask_id,   // [A,4]     f32
    float* __restrict__ out,             // [A,256]   f32  (output 0)
    float* __restrict__ out_alt,         // [A,256]   f32  (output 1)
    int n_areas)
{
    const int lane = threadIdx.x & 63;
    const int w    = blockIdx.x * (blockDim.x >> 6) + (threadIdx.x >> 6);
    const int area  = w >> 1;
    const int which = w & 1;                 // 0 -> mask/out, 1 -> mask_alt/out_alt
    if (area >= n_areas) return;

    const float* msk = which ? mask_alt : mask;   // wave-uniform select
    float*       dst = which ? out_alt  : out;

    const size_t pix = (size_t)area * 256 + (size_t)lane * 4;

    // Issue all VMEM up front; compute hb while loads are in flight.
    float4 idv = *(const float4*)(mask_id + (size_t)area * 4);
    const float4* mp = (const float4*)(msk + pix * 4);
    float4 p0 = mp[0], p1 = mp[1], p2 = mp[2], p3 = mp[3];
    float4 im = *(const float4*)(img + pix);

    // Per-area id (wave-uniform): harder_diff_round, batched 4-wide.
    float hb[4] = { idv.x, idv.y, idv.z, idv.w };
    dround_batch<4>(hb); dround_batch<4>(hb); dround_batch<4>(hb);
    float vb[4];
#pragma unroll
    for (int k = 0; k < 4; ++k) vb[k] = 1.0f - hb[k];

    float c[16] = { p0.x, p0.y, p0.z, p0.w,  p1.x, p1.y, p1.z, p1.w,
                    p2.x, p2.y, p2.z, p2.w,  p3.x, p3.y, p3.z, p3.w };

    // harder_diff_round(mask channels): 3 batches of 16 sins.
    dround_batch<16>(c); dround_batch<16>(c); dround_batch<16>(c);

    // differentiable_eq combine: t = a*hb + (1-a)*vb   (full-rate VALU)
#pragma unroll
    for (int i = 0; i < 16; ++i) {
        float om = 1.0f - c[i];
        c[i] = __builtin_fmaf(c[i], hb[i & 3], om * vb[i & 3]);
    }

    // harder_diff_round(eq): 3 batches of 16.
    dround_batch<16>(c); dround_batch<16>(c); dround_batch<16>(c);

    // differentiable_and tree: dround each channel once (1 batch of 16),
    // pairwise products, then dround the two partials (batch of 8), product.
    dround_batch<16>(c);
    float p[8];
#pragma unroll
    for (int j = 0; j < 4; ++j) {
        p[2*j]   = c[4*j]   * c[4*j+1];
        p[2*j+1] = c[4*j+2] * c[4*j+3];
    }
    dround_batch<8>(p);

    float imv[4] = { im.x, im.y, im.z, im.w };
    float m[4];
    float sm = 0.f, si = 0.f;
#pragma unroll
    for (int j = 0; j < 4; ++j) {
        m[j] = p[2*j] * p[2*j+1];
        sm += m[j]; si += m[j] * imv[j];
    }

    // Wave-wide butterfly reduction (64 lanes) for num/den.
#pragma unroll
    for (int off = 32; off; off >>= 1) {
        sm += __shfl_xor(sm, off, 64);
        si += __shfl_xor(si, off, 64);
    }

    // Guard 0/0: m >= 0 sums, so sm==0 implies every m==0 -> output 0.
    const float mean = (sm > 0.f) ? (si / sm) : 0.f;

    float4 o;
    o.x = m[0] * mean; o.y = m[1] * mean; o.z = m[2] * mean; o.w = m[3] * mean;
    *(float4*)(dst + pix) = o;                               // 16 B/lane, coalesced
}

extern "C" void kernel_launch(void* const* d_in, const int* in_sizes, int n_in,
                              void* d_out, int out_size, void* d_ws, size_t ws_size,
                              hipStream_t stream) {
    // setup_inputs() order (all float32 per reference):
    // 0: resized_image      [B,N,16,16,1]
    // 1: mask_combined      [B,N,16,16,4]
    // 2: mask_combined_alt  [B,N,16,16,4]
    // 3: initial_mask_id    [B,N,4]
    // 4: mask_new_bi_channel (unused)
    // 5: mask_index          (unused)
    const float* img      = (const float*)d_in[0];
    const float* mask     = (const float*)d_in[1];
    const float* mask_alt = (const float*)d_in[2];
    const float* mask_id  = (const float*)d_in[3];

    const int n_areas = out_size / 512;             // B*N = 16384
    float* out     = (float*)d_out;
    float* out_alt = out + (size_t)n_areas * 256;

    // 2 waves per area (one per mask variant), 4 waves per 256-thread block.
    const int n_waves = n_areas * 2;
    const int waves_per_block = 4;
    const int blocks = (n_waves + waves_per_block - 1) / waves_per_block;
    De_conv_areas_kernel<<<blocks, 256, 0, stream>>>(
        img, mask, mask_alt, mask_id, out, out_alt, n_areas);
}

// Round 7
// 189.326 us; speedup vs baseline: 1.0090x; 1.0090x over previous
//
#include <hip/hip_runtime.h>

#define INV_2PI 0.15915494309189535f

// v_sin_f32 takes REVOLUTIONS: computes sin(2*pi*x) directly, no range
// reduction. volatile asm pins the relative order of the sins so the
// compiler CANNOT re-interleave them with their consumers (which would
// serialize the wave on in-order issue: fma_i stalls before sin_{i+1}).
// gfx9-lineage trans ops are HW-interlocked -> no manual s_nop needed.
__device__ __forceinline__ float vsin_pinned(float x) {
    float r;
    asm volatile("v_sin_f32 %0, %1" : "=v"(r) : "v"(x));
    return r;
}

// Batched diff_round: N independent sins issue back-to-back through the
// trans pipe, then N fmas whose operands are already long-ready.
template <int N>
__device__ __forceinline__ void dround_batch(float* c) {
    float s[N];
#pragma unroll
    for (int i = 0; i < N; ++i) s[i] = vsin_pinned(c[i]);
#pragma unroll
    for (int i = 0; i < N; ++i) c[i] = __builtin_fmaf(-INV_2PI, s[i], c[i]);
}

// One wave (64 lanes) per (area, mask-variant); each lane owns 4 contiguous
// pixels (16 mask channels) kept live in c[16]: every diff_round stage is a
// batch of 16 independent sins -> trans-pipe ILP instead of latency chains.
__global__ __launch_bounds__(256) void De_conv_areas_kernel(
    const float* __restrict__ img,       // [A,256,1] f32
    const float* __restrict__ mask,      // [A,256,4] f32
    const float* __restrict__ mask_alt,  // [A,256,4] f32
    const float* __restrict__ mask_id,   // [A,4]     f32
    float* __restrict__ out,             // [A,256]   f32  (output 0)
    float* __restrict__ out_alt,         // [A,256]   f32  (output 1)
    int n_areas)
{
    const int lane = threadIdx.x & 63;
    const int w    = blockIdx.x * (blockDim.x >> 6) + (threadIdx.x >> 6);
    const int area  = w >> 1;
    const int which = w & 1;                 // 0 -> mask/out, 1 -> mask_alt/out_alt
    if (area >= n_areas) return;

    const float* msk = which ? mask_alt : mask;   // wave-uniform select
    float*       dst = which ? out_alt  : out;

    const size_t pix = (size_t)area * 256 + (size_t)lane * 4;

    // Issue all VMEM up front; loads in flight while hb is computed.
    float4 idv = *(const float4*)(mask_id + (size_t)area * 4);
    const float4* mp = (const float4*)(msk + pix * 4);
    float4 p0 = mp[0], p1 = mp[1], p2 = mp[2], p3 = mp[3];
    float4 im = *(const float4*)(img + pix);

    // Per-area id (wave-uniform): harder_diff_round, batched 4-wide.
    float hb[4] = { idv.x, idv.y, idv.z, idv.w };
    dround_batch<4>(hb); dround_batch<4>(hb); dround_batch<4>(hb);
    float vb[4];
#pragma unroll
    for (int k = 0; k < 4; ++k) vb[k] = 1.0f - hb[k];

    float c[16] = { p0.x, p0.y, p0.z, p0.w,  p1.x, p1.y, p1.z, p1.w,
                    p2.x, p2.y, p2.z, p2.w,  p3.x, p3.y, p3.z, p3.w };

    // harder_diff_round(mask channels): 3 pinned batches of 16 sins.
    dround_batch<16>(c); dround_batch<16>(c); dround_batch<16>(c);

    // differentiable_eq combine: t = a*hb + (1-a)*vb   (full-rate VALU)
#pragma unroll
    for (int i = 0; i < 16; ++i) {
        float om = 1.0f - c[i];
        c[i] = __builtin_fmaf(c[i], hb[i & 3], om * vb[i & 3]);
    }

    // harder_diff_round(eq): 3 pinned batches of 16.
    dround_batch<16>(c); dround_batch<16>(c); dround_batch<16>(c);

    // differentiable_and tree: dround each channel once (1 batch of 16),
    // pairwise products, dround the partials (batch of 8), final product.
    dround_batch<16>(c);
    float p[8];
#pragma unroll
    for (int j = 0; j < 4; ++j) {
        p[2*j]   = c[4*j]   * c[4*j+1];
        p[2*j+1] = c[4*j+2] * c[4*j+3];
    }
    dround_batch<8>(p);

    float imv[4] = { im.x, im.y, im.z, im.w };
    float m[4];
    float sm = 0.f, si = 0.f;
#pragma unroll
    for (int j = 0; j < 4; ++j) {
        m[j] = p[2*j] * p[2*j+1];
        sm += m[j]; si += m[j] * imv[j];
    }

    // Wave-wide butterfly reduction (64 lanes) for num/den.
#pragma unroll
    for (int off = 32; off; off >>= 1) {
        sm += __shfl_xor(sm, off, 64);
        si += __shfl_xor(si, off, 64);
    }

    // Guard 0/0: m >= 0 sums, so sm==0 implies every m==0 -> output 0.
    const float mean = (sm > 0.f) ? (si / sm) : 0.f;

    float4 o;
    o.x = m[0] * mean; o.y = m[1] * mean; o.z = m[2] * mean; o.w = m[3] * mean;
    *(float4*)(dst + pix) = o;                               // 16 B/lane, coalesced
}

extern "C" void kernel_launch(void* const* d_in, const int* in_sizes, int n_in,
                              void* d_out, int out_size, void* d_ws, size_t ws_size,
                              hipStream_t stream) {
    // setup_inputs() order (all float32 per reference):
    // 0: resized_image      [B,N,16,16,1]
    // 1: mask_combined      [B,N,16,16,4]
    // 2: mask_combined_alt  [B,N,16,16,4]
    // 3: initial_mask_id    [B,N,4]
    // 4: mask_new_bi_channel (unused)
    // 5: mask_index          (unused)
    const float* img      = (const float*)d_in[0];
    const float* mask     = (const float*)d_in[1];
    const float* mask_alt = (const float*)d_in[2];
    const float* mask_id  = (const float*)d_in[3];

    const int n_areas = out_size / 512;             // B*N = 16384
    float* out     = (float*)d_out;
    float* out_alt = out + (size_t)n_areas * 256;

    // 2 waves per area (one per mask variant), 4 waves per 256-thread block.
    const int n_waves = n_areas * 2;
    const int waves_per_block = 4;
    const int blocks = (n_waves + waves_per_block - 1) / waves_per_block;
    De_conv_areas_kernel<<<blocks, 256, 0, stream>>>(
        img, mask, mask_alt, mask_id, out, out_alt, n_areas);
}